// Round 5
// baseline (197.520 us; speedup 1.0000x reference)
//
#include <hip/hip_runtime.h>
#include <math.h>

// Problem constants (B=4, S=2048, H=1024, E=16, TOP_K=4)
constexpr int kTokens = 8192;   // B*S
constexpr int kH      = 1024;
constexpr int kE      = 16;
constexpr int kTopK   = 4;
constexpr int kNC     = 16;     // h-splits (64 h each)

// ---------------------------------------------------------------------------
// Stage 1 v5: barrier-free wave-private staging (r4, proven correct) +
// depth-3 register load pipeline + conflict-free LDS banking.
//
// Post-mortem r4: removing barriers left dur at ~54 us but VALUBusy 16->39%
// and bank conflicts 262k->1.31M (write pattern at stride 12 collides);
// prefetch lead was only ~1 compute-phase (~300cyc) vs 600-900cyc latency.
// Fix: (1) 3 register sets, fully unrolled rotation: pass p ds_writes
// data(p+1) issued TWO passes earlier (lead >1000cyc) and issues data(p+3);
// compiler emits counted vmcnt(2) at each TWRITE (T4: loads in flight across
// passes, never drained). (2) S=8 floats/row wave-private tiles: write
// granule (2*rA+c2)%8 tiles all 8 bank-granules (conflict-free); read
// granule (2*ln+k4)%8 is 2-way (free per m136). LDS 20.5 KB.
// Numerics = proven scheme: fp32 accum per 16-h chunk, fp64 fold, fp64
// cross-wave reduce, fp32 partial per 64 h. Weights via wave-uniform s_load.
// ---------------------------------------------------------------------------
__global__ __launch_bounds__(256, 5)
void router_fmac(const float* __restrict__ x,   const float* __restrict__ img,
                 const float* __restrict__ txt, const float* __restrict__ aud,
                 const float* __restrict__ Wg,  const float* __restrict__ Wi,
                 const float* __restrict__ Wt,  const float* __restrict__ Wa,
                 float* __restrict__ partials)
{
    // 20.5 KB: two wave-private tile regions [4 waves][64 rows][8 floats]
    // (buf0 = smem+w*512, buf1 = smem+2048+w*512); epilogue reuses words
    // 0..5119 as red[4][64][20] after a real barrier.
    __shared__ float smem[5120];

    const int t  = threadIdx.x;
    const int w  = __builtin_amdgcn_readfirstlane(t >> 6);  // wave id (SGPR)
    const int ln = t & 63;                                  // lane = token
    const int hs    = blockIdx.x & 15;   // h-split
    const int tg    = blockIdx.x >> 4;   // token group
    const int tok0  = tg * 64;
    const int hbase = hs * 64;

    const float* Xs[4] = { x,  img, txt, aud };
    const float* Ws[4] = { Wg, Wi,  Wt,  Wa  };

    // wave-private staging: lane covers rows (rA, rA+32), 16B at col c2*16
    // of THIS wave's 8-float h-slice (32B dense per row-pair of lanes).
    const int c2 = ln & 1;
    const int rA = ln >> 1;   // 0..31

    // per-lane float offset within one modality plane (sans the s*32 term)
    const size_t loff = (size_t)(tok0 + rA) * kH + hbase + w * 8 + c2 * 4;

    float* wb0 = smem + w * 512;           // this wave's buffer-0 (64x8)
    float* wb1 = smem + 2048 + w * 512;    // buffer-1

    float4 A0, A1, B0, B1, C0, C1;

#define ISSUE(Rx, Ry, p) { \
    const float* s_ = Xs[(p) >> 1] + loff + ((p) & 1) * 32; \
    Rx = *(const float4*)(s_); \
    Ry = *(const float4*)(s_ + (size_t)32 * kH); }

    // write granule (2*rA + c2) % 8: perfect 8-tile -> conflict-free
#define TWRITE(bufp, Rx, Ry) { \
    *(float4*)&(bufp)[rA * 8 + c2 * 4]        = Rx; \
    *(float4*)&(bufp)[(rA + 32) * 8 + c2 * 4] = Ry; }

#define FENCE() { asm volatile("s_waitcnt lgkmcnt(0)" ::: "memory"); \
                  __builtin_amdgcn_sched_barrier(0); }

    double dacc[kE];
#pragma unroll
    for (int e = 0; e < kE; ++e) dacc[e] = 0.0;
    float facc[kE];

#define RESET() { _Pragma("unroll") for (int e = 0; e < kE; ++e) facc[e] = 0.f; }
#define FOLD()  { _Pragma("unroll") for (int e = 0; e < kE; ++e) dacc[e] += (double)facc[e]; }

    // read granule (2*ln + k4) % 8: 2-way aliasing = free (m136)
#define COMPUTE(bufp, p) { \
    const float* wbase = Ws[(p) >> 1] + (size_t)(hbase + ((p) & 1) * 32 + w * 8) * kE; \
    _Pragma("unroll") for (int k4 = 0; k4 < 2; ++k4) { \
        const float4 xv = *(const float4*)&(bufp)[ln * 8 + k4 * 4]; \
        _Pragma("unroll") for (int j = 0; j < 4; ++j) { \
            const float xh = (j == 0) ? xv.x : (j == 1) ? xv.y : (j == 2) ? xv.z : xv.w; \
            const float* wr = wbase + (k4 * 4 + j) * kE;   /* wave-uniform -> s_load */ \
            const float4 w0 = *(const float4*)(wr + 0); \
            const float4 w1 = *(const float4*)(wr + 4); \
            const float4 w2 = *(const float4*)(wr + 8); \
            const float4 w3 = *(const float4*)(wr + 12); \
            facc[0]  += xh * w0.x;  facc[1]  += xh * w0.y; \
            facc[2]  += xh * w0.z;  facc[3]  += xh * w0.w; \
            facc[4]  += xh * w1.x;  facc[5]  += xh * w1.y; \
            facc[6]  += xh * w1.z;  facc[7]  += xh * w1.w; \
            facc[8]  += xh * w2.x;  facc[9]  += xh * w2.y; \
            facc[10] += xh * w2.z;  facc[11] += xh * w2.w; \
            facc[12] += xh * w3.x;  facc[13] += xh * w3.y; \
            facc[14] += xh * w3.z;  facc[15] += xh * w3.w; \
        } } }

    // ---- prologue: 3 passes of loads in flight ----
    ISSUE(A0, A1, 0);  ISSUE(B0, B1, 1);  ISSUE(C0, C1, 2);
    TWRITE(wb0, A0, A1);                  // waits only its own 2 loads
    FENCE();

    // pass p: TWRITE wb[(p+1)&1] <- data(p+1) (issued at p-2, counted vmcnt);
    //         ISSUE data(p+3); COMPUTE wb[p&1] = data(p); fence (wave-local).
    TWRITE(wb1, B0, B1);  ISSUE(A0, A1, 3);  RESET(); COMPUTE(wb0, 0);          FENCE(); // p0
    TWRITE(wb0, C0, C1);  ISSUE(B0, B1, 4);           COMPUTE(wb1, 1);  FOLD(); FENCE(); // p1
    TWRITE(wb1, A0, A1);  ISSUE(C0, C1, 5);  RESET(); COMPUTE(wb0, 2);          FENCE(); // p2
    TWRITE(wb0, B0, B1);  ISSUE(A0, A1, 6);           COMPUTE(wb1, 3);  FOLD(); FENCE(); // p3
    TWRITE(wb1, C0, C1);  ISSUE(B0, B1, 7);  RESET(); COMPUTE(wb0, 4);          FENCE(); // p4
    TWRITE(wb0, A0, A1);                              COMPUTE(wb1, 5);  FOLD(); FENCE(); // p5
    TWRITE(wb1, B0, B1);                     RESET(); COMPUTE(wb0, 6);          FENCE(); // p6
                                                      COMPUTE(wb1, 7);  FOLD();         // p7

#undef ISSUE
#undef TWRITE
#undef FENCE
#undef RESET
#undef FOLD
#undef COMPUTE

    // ---- epilogue: cross-wave fp64 reduce (the only real barriers) ----
    __syncthreads();   // all waves done with private buffers before overwrite
#pragma unroll
    for (int q = 0; q < 4; ++q) {
        *(float4*)&smem[(w * 64 + ln) * 20 + q * 4] =
            make_float4((float)dacc[q * 4 + 0], (float)dacc[q * 4 + 1],
                        (float)dacc[q * 4 + 2], (float)dacc[q * 4 + 3]);
    }
    __syncthreads();
    {
        const int tok = t >> 2;
        const int eq  = t & 3;
        double s0 = 0.0, s1 = 0.0, s2 = 0.0, s3 = 0.0;
#pragma unroll
        for (int ww = 0; ww < 4; ++ww) {
            const float4 v = *(const float4*)&smem[(ww * 64 + tok) * 20 + eq * 4];
            s0 += (double)v.x;  s1 += (double)v.y;
            s2 += (double)v.z;  s3 += (double)v.w;
        }
        // TRANSPOSED partials [tok][chunk][e]: stage-2 streams each token's
        // 1KB contiguously; this 64B-granule scattered store is benign.
        *(float4*)&partials[((size_t)(tok0 + tok) * kNC + hs) * kE + eq * 4] =
            make_float4((float)s0, (float)s1, (float)s2, (float)s3);
    }
}

// ---------------------------------------------------------------------------
// Stage 2 v3: 256 blocks x 32 tokens; partials in [tok][chunk][e] layout so
// each block streams 32 contiguous 1KB token records (fully coalesced).
// Thread (tq, eq, hc): sums 8 of the 16 chunk-partials for its e-quad in
// fp64; halves combined deterministically in LDS. Softmax/top-k unchanged.
// ---------------------------------------------------------------------------
__global__ __launch_bounds__(256)
void router_topk(const float* __restrict__ partials,
                 const float* __restrict__ bg, const float* __restrict__ bi,
                 const float* __restrict__ bt, const float* __restrict__ ba,
                 float* __restrict__ out, float* __restrict__ blocksum)
{
    __shared__ double lgs[32][2][kE + 2];
    __shared__ float  pr[32][kE + 1];

    const int t    = threadIdx.x;
    const int tq   = t >> 3;        // token 0..31
    const int eq   = (t >> 1) & 3;  // e-quad
    const int hc   = t & 1;         // chunk half (c 0..7 vs 8..15)
    const int tok0 = blockIdx.x * 32;

    double a0 = 0.0, a1 = 0.0, a2 = 0.0, a3 = 0.0;
    if (hc == 0) {  // biases added exactly once, in the low half
        a0 = (double)bg[eq*4+0] + (double)bi[eq*4+0] + (double)bt[eq*4+0] + (double)ba[eq*4+0];
        a1 = (double)bg[eq*4+1] + (double)bi[eq*4+1] + (double)bt[eq*4+1] + (double)ba[eq*4+1];
        a2 = (double)bg[eq*4+2] + (double)bi[eq*4+2] + (double)bt[eq*4+2] + (double)ba[eq*4+2];
        a3 = (double)bg[eq*4+3] + (double)bi[eq*4+3] + (double)bt[eq*4+3] + (double)ba[eq*4+3];
    }

#pragma unroll
    for (int c8 = 0; c8 < 8; ++c8) {
        const int c = hc * 8 + c8;
        const float4 v = *(const float4*)(partials +
            ((size_t)(tok0 + tq) * kNC + c) * kE + eq * 4);
        a0 += (double)v.x;  a1 += (double)v.y;  a2 += (double)v.z;  a3 += (double)v.w;
    }
    lgs[tq][hc][eq*4+0] = a0;  lgs[tq][hc][eq*4+1] = a1;
    lgs[tq][hc][eq*4+2] = a2;  lgs[tq][hc][eq*4+3] = a3;
    __syncthreads();

    if (t < 32) {
        const int tok = tok0 + t;
        double lg[kE];
#pragma unroll
        for (int e = 0; e < kE; ++e) lg[e] = lgs[t][0][e] + lgs[t][1][e];

        double mx = lg[0];
#pragma unroll
        for (int e = 1; e < kE; ++e) mx = fmax(mx, lg[e]);

        float p[kE];
        float sum = 0.f;
#pragma unroll
        for (int e = 0; e < kE; ++e) {
            p[e] = expf((float)(lg[e] - mx));
            sum += p[e];
        }
        const float inv = 1.f / sum;
#pragma unroll
        for (int e = 0; e < kE; ++e) { p[e] *= inv; pr[t][e] = p[e]; }

        // top-4, descending, ties -> smallest index (matches jax.lax.top_k)
        unsigned used = 0;
        float tp[kTopK];
        int   ti[kTopK];
        float s4 = 0.f;
#pragma unroll
        for (int k = 0; k < kTopK; ++k) {
            float best = -1.f;
            int   bidx = 0;
#pragma unroll
            for (int e = 0; e < kE; ++e) {
                if (!((used >> e) & 1u) && p[e] > best) { best = p[e]; bidx = e; }
            }
            used |= 1u << bidx;
            tp[k] = best;
            ti[k] = bidx;
            s4 += best;
        }
        const float rn = 1.f / s4;

        *(float4*)&out[(size_t)tok * kTopK] =
            make_float4((float)ti[0], (float)ti[1], (float)ti[2], (float)ti[3]);
        *(float4*)&out[(size_t)kTokens * kTopK + (size_t)tok * kTopK] =
            make_float4(tp[0] * rn, tp[1] * rn, tp[2] * rn, tp[3] * rn);
    }
    __syncthreads();

    if (t < kE) {
        float s = 0.f;
#pragma unroll
        for (int tk = 0; tk < 32; ++tk) s += pr[tk][t];
        blocksum[blockIdx.x * kE + t] = s;
    }
}

// ---------------------------------------------------------------------------
// Stage 3: 256 block-partials -> mean prob per expert -> aux loss scalar.
// 256 threads x 16 coalesced loads + fp64 LDS tree. Deterministic.
// ---------------------------------------------------------------------------
__global__ __launch_bounds__(256)
void router_aux(const float* __restrict__ blocksum, float* __restrict__ out)
{
    __shared__ double ps[16][kE];
    __shared__ double fin[kE];
    const int t = threadIdx.x;
    {
        const int e  = t & 15;
        const int bq = t >> 4;   // 0..15
        double s = 0.0;
#pragma unroll
        for (int k = 0; k < 16; ++k)
            s += (double)blocksum[(bq * 16 + k) * kE + e];
        ps[bq][e] = s;
    }
    __syncthreads();
    if (t < kE) {
        double s = 0.0;
#pragma unroll
        for (int q = 0; q < 16; ++q) s += ps[q][t];
        fin[t] = s / (double)kTokens;
    }
    __syncthreads();
    if (t == 0) {
        double aux = 0.0;
#pragma unroll
        for (int e = 0; e < kE; ++e) aux += fin[e] * log(fin[e] * (double)kE + 1e-9);
        out[(size_t)kTokens * kTopK * 2] = (float)aux;  // element 65536
    }
}

extern "C" void kernel_launch(void* const* d_in, const int* in_sizes, int n_in,
                              void* d_out, int out_size, void* d_ws, size_t ws_size,
                              hipStream_t stream)
{
    const float* x   = (const float*)d_in[0];
    const float* img = (const float*)d_in[1];
    const float* txt = (const float*)d_in[2];
    const float* aud = (const float*)d_in[3];
    const float* Wg  = (const float*)d_in[4];
    const float* bg  = (const float*)d_in[5];
    const float* Wi  = (const float*)d_in[6];
    const float* bi  = (const float*)d_in[7];
    const float* Wt  = (const float*)d_in[8];
    const float* bt  = (const float*)d_in[9];
    const float* Wa  = (const float*)d_in[10];
    const float* ba  = (const float*)d_in[11];

    float* out      = (float*)d_out;
    float* partials = (float*)d_ws;   // [8192][16][16] fp32 = 8 MB
    float* blocksum = (float*)((char*)d_ws + (size_t)kTokens * kNC * kE * 4);  // 16 KB

    router_fmac<<<2048, 256, 0, stream>>>(x, img, txt, aud, Wg, Wi, Wt, Wa, partials);
    router_topk<<<256, 256, 0, stream>>>(partials, bg, bi, bt, ba, out, blocksum);
    router_aux<<<1, 256, 0, stream>>>(blocksum, out);
}

// Round 6
// 192.676 us; speedup vs baseline: 1.0251x; 1.0251x over previous
//
#include <hip/hip_runtime.h>
#include <math.h>

// Problem constants (B=4, S=2048, H=1024, E=16, TOP_K=4)
constexpr int kTokens = 8192;   // B*S
constexpr int kH      = 1024;
constexpr int kE      = 16;
constexpr int kTopK   = 4;
constexpr int kNC     = 16;     // h-splits (64 h each)

// ---------------------------------------------------------------------------
// Stage 1: r0 VERBATIM (proven 53-54us; every structural deviation in r3/r4/r5
// regressed). Block = 256 threads = 4 waves, 64 tokens, one 64-h split, all 4
// modalities; 8 passes of [64 tok][32 h] double-buffered LDS tiles (stride 36,
// proven conflict-class), depth-1 register prefetch, wave-uniform s_load
// weights, fp32 accum per 16-h chunk -> fp64 fold -> fp64 cross-wave reduce.
// ONLY changes vs r0: (1) epilogue store is TOKEN-MAJOR [tok][chunk][e]
// (empirically -38us on stage-2 in r4->r5 A/B); (2) block 0 zeroes the
// last-block ticket used by the fused stage-2/3.
// ---------------------------------------------------------------------------
__global__ __launch_bounds__(256, 5)
void router_fmac(const float* __restrict__ x,   const float* __restrict__ img,
                 const float* __restrict__ txt, const float* __restrict__ aud,
                 const float* __restrict__ Wg,  const float* __restrict__ Wi,
                 const float* __restrict__ Wt,  const float* __restrict__ Wa,
                 float* __restrict__ partials,  int* __restrict__ ticket)
{
    // 20 KB: two [64][36] tile buffers (stride 36 floats = 144 B: 16B-aligned,
    // bank-conflict-free per round-3 measurement); reused as red[4][64][20].
    __shared__ float smem[5120];

    const int t  = threadIdx.x;
    const int w  = __builtin_amdgcn_readfirstlane(t >> 6);  // wave id (SGPR)
    const int ln = t & 63;                                  // lane = token
    const int hs    = blockIdx.x & 15;   // h-split
    const int tg    = blockIdx.x >> 4;   // token group
    const int tok0  = tg * 64;
    const int hbase = hs * 64;

    if (blockIdx.x == 0 && t == 0) *ticket = 0;   // reset for fused aux

    const float* Xs[4] = { x,  img, txt, aud };
    const float* Ws[4] = { Wg, Wi,  Wt,  Wa  };

    // staging role: row sr (and sr+32), float4-col sc -> 8 rows x 128 B
    // contiguous per wave-instr (16 lines, same as r0).
    const int sc = t & 7;
    const int sr = t >> 3;   // 0..31

    // ---- prologue: stage pass 0 (modality 0, s=0) ----
    {
        const float* src = Xs[0] + (size_t)tok0 * kH + hbase + sc * 4;
        const float4 va = *(const float4*)(src + (size_t)sr * kH);
        const float4 vb = *(const float4*)(src + (size_t)(sr + 32) * kH);
        *(float4*)&smem[sr * 36 + sc * 4] = va;
        *(float4*)&smem[(sr + 32) * 36 + sc * 4] = vb;
    }
    __syncthreads();

    double dacc[kE];
#pragma unroll
    for (int e = 0; e < kE; ++e) dacc[e] = 0.0;
    float facc[kE];

#pragma unroll
    for (int p = 0; p < 8; ++p) {        // pass = (modality m = p>>1, half s = p&1)
        const int m = p >> 1;
        const int s = p & 1;

        // prefetch next pass's tile into registers (in flight during compute)
        float4 na, nb;
        if (p < 7) {
            const int m2 = (p + 1) >> 1, s2 = (p + 1) & 1;
            const float* src = Xs[m2] + (size_t)tok0 * kH + hbase + s2 * 32 + sc * 4;
            na = *(const float4*)(src + (size_t)sr * kH);
            nb = *(const float4*)(src + (size_t)(sr + 32) * kH);
        }

        if (s == 0) {
#pragma unroll
            for (int e = 0; e < kE; ++e) facc[e] = 0.f;
        }

        const float* buf   = smem + (p & 1) * 2304;
        const float* wbase = Ws[m] + (size_t)(hbase + s * 32 + w * 8) * kE; // wave-uniform

#pragma unroll
        for (int k4 = 0; k4 < 2; ++k4) {
            const float4 xv = *(const float4*)&buf[ln * 36 + w * 8 + k4 * 4];
#pragma unroll
            for (int j = 0; j < 4; ++j) {
                const float xh = (j == 0) ? xv.x : (j == 1) ? xv.y : (j == 2) ? xv.z : xv.w;
                const float* wr = wbase + (k4 * 4 + j) * kE;   // wave-uniform -> s_load
                const float4 w0 = *(const float4*)(wr + 0);
                const float4 w1 = *(const float4*)(wr + 4);
                const float4 w2 = *(const float4*)(wr + 8);
                const float4 w3 = *(const float4*)(wr + 12);
                facc[0]  += xh * w0.x;  facc[1]  += xh * w0.y;
                facc[2]  += xh * w0.z;  facc[3]  += xh * w0.w;
                facc[4]  += xh * w1.x;  facc[5]  += xh * w1.y;
                facc[6]  += xh * w1.z;  facc[7]  += xh * w1.w;
                facc[8]  += xh * w2.x;  facc[9]  += xh * w2.y;
                facc[10] += xh * w2.z;  facc[11] += xh * w2.w;
                facc[12] += xh * w3.x;  facc[13] += xh * w3.y;
                facc[14] += xh * w3.z;  facc[15] += xh * w3.w;
            }
        }

        if (s == 1) {   // fold 16-h fp32 chunk into fp64
#pragma unroll
            for (int e = 0; e < kE; ++e) dacc[e] += (double)facc[e];
        }

        // write prefetched tile into the other buffer; barrier ends the pass
        if (p < 7) {
            float* nbuf = smem + ((p + 1) & 1) * 2304;
            *(float4*)&nbuf[sr * 36 + sc * 4] = na;
            *(float4*)&nbuf[(sr + 32) * 36 + sc * 4] = nb;
        }
        __syncthreads();
    }

    // ---- cross-wave reduce: red[w][tok][e] (stride 20 floats, 16B-aligned) ----
#pragma unroll
    for (int q = 0; q < 4; ++q) {
        *(float4*)&smem[(w * 64 + ln) * 20 + q * 4] =
            make_float4((float)dacc[q * 4 + 0], (float)dacc[q * 4 + 1],
                        (float)dacc[q * 4 + 2], (float)dacc[q * 4 + 3]);
    }
    __syncthreads();
    {
        const int tok = t >> 2;
        const int eq  = t & 3;
        double s0 = 0.0, s1 = 0.0, s2 = 0.0, s3 = 0.0;
#pragma unroll
        for (int ww = 0; ww < 4; ++ww) {
            const float4 v = *(const float4*)&smem[(ww * 64 + tok) * 20 + eq * 4];
            s0 += (double)v.x;  s1 += (double)v.y;
            s2 += (double)v.z;  s3 += (double)v.w;
        }
        // TOKEN-MAJOR partials [tok][chunk][e]: stage-2 streams 1KB/token.
        *(float4*)&partials[((size_t)(tok0 + tok) * kNC + hs) * kE + eq * 4] =
            make_float4((float)s0, (float)s1, (float)s2, (float)s3);
    }
}

// ---------------------------------------------------------------------------
// Stage 2+3 fused: combine 16 chunk-partials + biases (fp64), softmax, top-k,
// output writes, per-block expert sums -- then the LAST block (device-scope
// ticket) reduces the 128 block-partials and writes the aux-loss scalar.
// Block = 64 tokens x 256 threads, 128 blocks (r0's proven geometry).
// Reads token-major partials: each block streams 64 contiguous 1KB records.
// ---------------------------------------------------------------------------
__global__ __launch_bounds__(256)
void router_topk(const float* __restrict__ partials,
                 const float* __restrict__ bg, const float* __restrict__ bi,
                 const float* __restrict__ bt, const float* __restrict__ ba,
                 float* __restrict__ out, float* __restrict__ blocksum,
                 int* __restrict__ ticket)
{
    __shared__ double lgs[64][kE + 1];
    __shared__ float  pr[64][kE + 1];
    __shared__ double ps[16][kE];
    __shared__ double fin[kE];
    __shared__ int    sticket;

    const int t    = threadIdx.x;
    const int tq   = t >> 2;      // token offset 0..63
    const int eq   = t & 3;       // e-quad
    const int tok0 = blockIdx.x * 64;

    double a0 = (double)bg[eq*4+0] + (double)bi[eq*4+0] + (double)bt[eq*4+0] + (double)ba[eq*4+0];
    double a1 = (double)bg[eq*4+1] + (double)bi[eq*4+1] + (double)bt[eq*4+1] + (double)ba[eq*4+1];
    double a2 = (double)bg[eq*4+2] + (double)bi[eq*4+2] + (double)bt[eq*4+2] + (double)ba[eq*4+2];
    double a3 = (double)bg[eq*4+3] + (double)bi[eq*4+3] + (double)bt[eq*4+3] + (double)ba[eq*4+3];

#pragma unroll
    for (int c = 0; c < kNC; ++c) {
        const float4 v = *(const float4*)(partials +
            ((size_t)(tok0 + tq) * kNC + c) * kE + eq * 4);
        a0 += (double)v.x;  a1 += (double)v.y;  a2 += (double)v.z;  a3 += (double)v.w;
    }
    lgs[tq][eq*4+0] = a0;  lgs[tq][eq*4+1] = a1;
    lgs[tq][eq*4+2] = a2;  lgs[tq][eq*4+3] = a3;
    __syncthreads();

    if (t < 64) {
        const int tok = tok0 + t;
        double lg[kE];
#pragma unroll
        for (int e = 0; e < kE; ++e) lg[e] = lgs[t][e];

        double mx = lg[0];
#pragma unroll
        for (int e = 1; e < kE; ++e) mx = fmax(mx, lg[e]);

        float p[kE];
        float sum = 0.f;
#pragma unroll
        for (int e = 0; e < kE; ++e) {
            p[e] = expf((float)(lg[e] - mx));
            sum += p[e];
        }
        const float inv = 1.f / sum;
#pragma unroll
        for (int e = 0; e < kE; ++e) { p[e] *= inv; pr[t][e] = p[e]; }

        // top-4, descending, ties -> smallest index (matches jax.lax.top_k)
        unsigned used = 0;
        float tp[kTopK];
        int   ti[kTopK];
        float s4 = 0.f;
#pragma unroll
        for (int k = 0; k < kTopK; ++k) {
            float best = -1.f;
            int   bidx = 0;
#pragma unroll
            for (int e = 0; e < kE; ++e) {
                if (!((used >> e) & 1u) && p[e] > best) { best = p[e]; bidx = e; }
            }
            used |= 1u << bidx;
            tp[k] = best;
            ti[k] = bidx;
            s4 += best;
        }
        const float rn = 1.f / s4;

        *(float4*)&out[(size_t)tok * kTopK] =
            make_float4((float)ti[0], (float)ti[1], (float)ti[2], (float)ti[3]);
        *(float4*)&out[(size_t)kTokens * kTopK + (size_t)tok * kTopK] =
            make_float4(tp[0] * rn, tp[1] * rn, tp[2] * rn, tp[3] * rn);
    }
    __syncthreads();

    if (t < kE) {
        float s = 0.f;
#pragma unroll
        for (int tk = 0; tk < 64; ++tk) s += pr[tk][t];
        blocksum[blockIdx.x * kE + t] = s;
    }

    // ---- fused aux: last block to arrive reduces all block-partials ----
    __threadfence();                 // make blocksum stores device-visible
    __syncthreads();                 // order all threads' stores before ticket
    if (t == 0) sticket = atomicAdd(ticket, 1);
    __syncthreads();
    if (sticket == (int)gridDim.x - 1) {
        __threadfence();             // acquire side
        const int e  = t & 15;
        const int bq = t >> 4;       // 0..15, 8 blocks each
        double s = 0.0;
#pragma unroll
        for (int k = 0; k < 8; ++k)
            s += (double)((volatile const float*)blocksum)[(bq * 8 + k) * kE + e];
        ps[bq][e] = s;
        __syncthreads();
        if (t < kE) {
            double s2 = 0.0;
#pragma unroll
            for (int q = 0; q < 16; ++q) s2 += ps[q][t];
            fin[t] = s2 / (double)kTokens;
        }
        __syncthreads();
        if (t == 0) {
            double aux = 0.0;
#pragma unroll
            for (int e2 = 0; e2 < kE; ++e2)
                aux += fin[e2] * log(fin[e2] * (double)kE + 1e-9);
            out[(size_t)kTokens * kTopK * 2] = (float)aux;  // element 65536
            *ticket = 0;             // self-reset for the next graph replay
        }
    }
}

extern "C" void kernel_launch(void* const* d_in, const int* in_sizes, int n_in,
                              void* d_out, int out_size, void* d_ws, size_t ws_size,
                              hipStream_t stream)
{
    const float* x   = (const float*)d_in[0];
    const float* img = (const float*)d_in[1];
    const float* txt = (const float*)d_in[2];
    const float* aud = (const float*)d_in[3];
    const float* Wg  = (const float*)d_in[4];
    const float* bg  = (const float*)d_in[5];
    const float* Wi  = (const float*)d_in[6];
    const float* bi  = (const float*)d_in[7];
    const float* Wt  = (const float*)d_in[8];
    const float* bt  = (const float*)d_in[9];
    const float* Wa  = (const float*)d_in[10];
    const float* ba  = (const float*)d_in[11];

    float* out      = (float*)d_out;
    float* partials = (float*)d_ws;   // [8192][16][16] fp32 = 8 MB
    float* blocksum = (float*)((char*)d_ws + (size_t)kTokens * kNC * kE * 4);  // 8 KB
    int*   ticket   = (int*)((char*)d_ws + (size_t)kTokens * kNC * kE * 4 + 128 * kE * 4);

    router_fmac<<<2048, 256, 0, stream>>>(x, img, txt, aud, Wg, Wi, Wt, Wa, partials, ticket);
    router_topk<<<128, 256, 0, stream>>>(partials, bg, bi, bt, ba, out, blocksum, ticket);
}